// Round 1
// baseline (12099.989 us; speedup 1.0000x reference)
//
#include <hip/hip_runtime.h>
#include <math.h>

#define B_  32
#define S_  64
#define T_  48
#define V_  32000
#define E_  512
#define H_  1024
#define G3  3072   // 3*H

// ---------------------------------------------------------------------------
// Tiled f32 GEMM:  C[m][n] = sum_k A[m][k] * W[n][k]  (+ bias[n])
// 128x128 tile, 256 threads, 8x8 per-thread microtile, BK=16.
// A rows optionally gathered through an id table (embedding lookup).
// out_mode 0: C[m*ldc + n]   (requires M % 128 == 0)
// out_mode 1: m = t*32+b -> C[b*(47*V) + t*V + n], rows m>=M skipped
// Grid: (N/128, ceil(M/128)), block 256. K multiple of 16, N multiple of 128.
// ---------------------------------------------------------------------------
__global__ __launch_bounds__(256, 2)
void gemm_bt(const float* __restrict__ A, int lda,
             const int* __restrict__ ids, int id_mode,  // 0 none, 1 enc b*64+t, 2 dec b*48+t
             const float* __restrict__ W, int ldw,
             const float* __restrict__ bias,
             float* __restrict__ C, int out_mode, int ldc,
             int M, int K)
{
    __shared__ __align__(16) float As[16][132];  // [k][m], stride 132: bank = (4k+m)%32
    __shared__ __align__(16) float Ws[16][132];  // [k][n]
    const int tid  = threadIdx.x;
    const int n0   = blockIdx.x * 128;
    const int m0   = blockIdx.y * 128;
    const int srow = tid >> 1;          // 0..127 staging row
    const int kq   = (tid & 1) * 8;     // 0 or 8

    long abase;
    {
        int m = m0 + srow;
        if (id_mode == 0) {
            abase = (long)m * lda;
        } else {
            int t = m >> 5, b = m & 31;
            int idx = (id_mode == 1) ? (b * S_ + t) : (b * T_ + t);
            abase = (long)ids[idx] * lda;
        }
    }
    const float* Ar = A + abase;
    const float* Wr = W + (long)(n0 + srow) * ldw;

    const int tx = (tid & 15) * 4;   // n offset 0..60 (plus +64 quadrant)
    const int ty = (tid >> 4) * 4;   // m offset 0..60 (plus +64 quadrant)
    float acc[8][8] = {};

    for (int k0 = 0; k0 < K; k0 += 16) {
        float4 a0 = *(const float4*)(Ar + k0 + kq);
        float4 a1 = *(const float4*)(Ar + k0 + kq + 4);
        float4 w0 = *(const float4*)(Wr + k0 + kq);
        float4 w1 = *(const float4*)(Wr + k0 + kq + 4);
        __syncthreads();   // previous iteration's reads complete
        As[kq+0][srow]=a0.x; As[kq+1][srow]=a0.y; As[kq+2][srow]=a0.z; As[kq+3][srow]=a0.w;
        As[kq+4][srow]=a1.x; As[kq+5][srow]=a1.y; As[kq+6][srow]=a1.z; As[kq+7][srow]=a1.w;
        Ws[kq+0][srow]=w0.x; Ws[kq+1][srow]=w0.y; Ws[kq+2][srow]=w0.z; Ws[kq+3][srow]=w0.w;
        Ws[kq+4][srow]=w1.x; Ws[kq+5][srow]=w1.y; Ws[kq+6][srow]=w1.z; Ws[kq+7][srow]=w1.w;
        __syncthreads();
#pragma unroll
        for (int k = 0; k < 16; ++k) {
            float4 a0v = *(const float4*)&As[k][ty];
            float4 a1v = *(const float4*)&As[k][ty + 64];
            float4 w0v = *(const float4*)&Ws[k][tx];
            float4 w1v = *(const float4*)&Ws[k][tx + 64];
            float av[8] = {a0v.x, a0v.y, a0v.z, a0v.w, a1v.x, a1v.y, a1v.z, a1v.w};
            float wv[8] = {w0v.x, w0v.y, w0v.z, w0v.w, w1v.x, w1v.y, w1v.z, w1v.w};
#pragma unroll
            for (int i = 0; i < 8; ++i)
#pragma unroll
                for (int j = 0; j < 8; ++j)
                    acc[i][j] += av[i] * wv[j];
        }
    }

    float4 bv0 = make_float4(0.f, 0.f, 0.f, 0.f);
    float4 bv1 = bv0;
    if (bias) {
        bv0 = *(const float4*)(bias + n0 + tx);
        bv1 = *(const float4*)(bias + n0 + tx + 64);
    }
#pragma unroll
    for (int i = 0; i < 8; ++i) {
        int m = m0 + ty + (i & 3) + (i >> 2) * 64;
        float4 o0, o1;
        o0.x = acc[i][0] + bv0.x; o0.y = acc[i][1] + bv0.y;
        o0.z = acc[i][2] + bv0.z; o0.w = acc[i][3] + bv0.w;
        o1.x = acc[i][4] + bv1.x; o1.y = acc[i][5] + bv1.y;
        o1.z = acc[i][6] + bv1.z; o1.w = acc[i][7] + bv1.w;
        if (out_mode == 0) {
            *(float4*)(C + (long)m * ldc + n0 + tx)      = o0;
            *(float4*)(C + (long)m * ldc + n0 + tx + 64) = o1;
        } else if (m < M) {
            int t = m >> 5, b2 = m & 31;
            float* cr = C + (long)b2 * ((T_-1)*V_) + (long)t * V_;
            *(float4*)(cr + n0 + tx)      = o0;
            *(float4*)(cr + n0 + tx + 64) = o1;
        }
    }
}

// ---------------------------------------------------------------------------
// Fused GRU step. Each block now owns TWO output units (j0, j0+1) so the
// h / x vectors are loaded once and reused across 2 units x 3 gates
// (halves the h-broadcast L2 traffic vs one-unit blocks).
// Block: 256 thr = (b 0..31) x (ks 0..7, K-slice of 128). Grid: 512.
// W rows are read with wave-broadcast addresses (2 distinct addrs per wave).
// ---------------------------------------------------------------------------
template<int HAS_X, int HAS_GI>
__global__ __launch_bounds__(256)
void gru_layer(const float* __restrict__ x, int xld,
               const float* __restrict__ wx, int wxld, int wxoff,
               const float* __restrict__ bih,
               const float* __restrict__ gi_pre,   // row stride G3, rows = b (bias included)
               const float* __restrict__ h,
               const float* __restrict__ whh,
               const float* __restrict__ bhh,
               float* __restrict__ h_new,
               float* __restrict__ seq_out, long seq_stride)
{
    const int j0  = blockIdx.x * 2;
    const int tid = threadIdx.x;
    const int b   = tid & 31;
    const int ks  = tid >> 5;
    __shared__ float redh[2][3][8][32];
    __shared__ float redx[2][3][8][32];

    const float* hr  = h + (long)b * H_;
    const float* wh  = whh + (long)j0 * H_;            // row (g*H+j0+u) = wh + (g*H+u)*H
    const float* xr  = nullptr;
    const float* wxb = nullptr;
    if (HAS_X) {
        xr  = x + (long)b * xld;
        wxb = wx + (long)j0 * wxld + wxoff;            // row (g*H+j0+u) = wxb + (g*H+u)*wxld
    }

    float ah[2][3] = {};
    float ax[2][3] = {};
    const int k0 = ks * 128;
#pragma unroll 2
    for (int k = k0; k < k0 + 128; k += 4) {
        float4 hv = *(const float4*)(hr + k);
        float4 xv;
        if (HAS_X) xv = *(const float4*)(xr + k);
#pragma unroll
        for (int u = 0; u < 2; ++u) {
#pragma unroll
            for (int g = 0; g < 3; ++g) {
                float4 wv = *(const float4*)(wh + ((long)g * H_ + u) * H_ + k);
                ah[u][g] += hv.x*wv.x + hv.y*wv.y + hv.z*wv.z + hv.w*wv.w;
                if (HAS_X) {
                    float4 uv = *(const float4*)(wxb + ((long)g * H_ + u) * wxld + k);
                    ax[u][g] += xv.x*uv.x + xv.y*uv.y + xv.z*uv.z + xv.w*uv.w;
                }
            }
        }
    }
#pragma unroll
    for (int u = 0; u < 2; ++u)
#pragma unroll
        for (int g = 0; g < 3; ++g) {
            redh[u][g][ks][b] = ah[u][g];
            if (HAS_X) redx[u][g][ks][b] = ax[u][g];
        }
    __syncthreads();
    if (tid < 64) {
        const int u  = tid >> 5;
        const int bb = tid & 31;
        const int j  = j0 + u;
        float gh0 = bhh[j], gh1 = bhh[H_ + j], gh2 = bhh[2*H_ + j];
#pragma unroll
        for (int q = 0; q < 8; ++q) {
            gh0 += redh[u][0][q][bb]; gh1 += redh[u][1][q][bb]; gh2 += redh[u][2][q][bb];
        }
        float gi0, gi1, gi2;
        if (HAS_GI) {
            const float* g = gi_pre + (long)bb * G3;
            gi0 = g[j]; gi1 = g[H_ + j]; gi2 = g[2*H_ + j];
        } else {
            gi0 = bih[j]; gi1 = bih[H_ + j]; gi2 = bih[2*H_ + j];
        }
        if (HAS_X) {
#pragma unroll
            for (int q = 0; q < 8; ++q) {
                gi0 += redx[u][0][q][bb]; gi1 += redx[u][1][q][bb]; gi2 += redx[u][2][q][bb];
            }
        }
        float r = 1.f / (1.f + expf(-(gi0 + gh0)));
        float z = 1.f / (1.f + expf(-(gi1 + gh1)));
        float n = tanhf(gi2 + r * gh2);
        float hv = h[(long)bb * H_ + j];
        float o = (1.f - z) * n + z * hv;
        h_new[(long)bb * H_ + j] = o;
        if (seq_out) seq_out[(long)bb * seq_stride + j] = o;
    }
}

// ---------------------------------------------------------------------------
// Attention for one decoder step. Grid: 32 (b). Block: 256.
// score[s] = proj[b][s][:] . d1[b][:]  (masked), softmax, ctx = attn @ enc_out
// ctx written to ctx_out + b*2048 (second half of cat row).
// ---------------------------------------------------------------------------
__global__ __launch_bounds__(256)
void attention_kernel(const float* __restrict__ proj,
                      const float* __restrict__ enc_out,
                      const int* __restrict__ src_ids,
                      const float* __restrict__ d1,
                      float* __restrict__ ctx_out)
{
    const int b = blockIdx.x;
    const int tid = threadIdx.x;
    __shared__ __align__(16) float dl[H_];
    __shared__ float attn[S_];

    *(float4*)&dl[tid * 4] = *(const float4*)(d1 + (long)b * H_ + tid * 4);
    __syncthreads();

    const int lane = tid & 63, wid = tid >> 6;
    for (int s = wid; s < S_; s += 4) {
        const float* pr = proj + ((long)b * S_ + s) * H_;
        float a = 0.f;
#pragma unroll
        for (int c = 0; c < 4; ++c) {
            float4 pv = *(const float4*)(pr + c * 256 + lane * 4);
            float4 dv = *(const float4*)&dl[c * 256 + lane * 4];
            a += pv.x*dv.x + pv.y*dv.y + pv.z*dv.z + pv.w*dv.w;
        }
#pragma unroll
        for (int off = 32; off > 0; off >>= 1) a += __shfl_xor(a, off);
        if (lane == 0) attn[s] = (src_ids[b * S_ + s] != 0) ? a : -1e9f;
    }
    __syncthreads();
    if (tid < 64) {
        float v = attn[tid];
        float mx = v;
#pragma unroll
        for (int off = 32; off > 0; off >>= 1) mx = fmaxf(mx, __shfl_xor(mx, off));
        float e = expf(v - mx);
        float sm = e;
#pragma unroll
        for (int off = 32; off > 0; off >>= 1) sm += __shfl_xor(sm, off);
        attn[tid] = e / sm;
    }
    __syncthreads();
    float4 acc = make_float4(0.f, 0.f, 0.f, 0.f);
    const float* eb = enc_out + (long)b * S_ * H_ + tid * 4;
    for (int s = 0; s < S_; ++s) {
        float w = attn[s];
        float4 ev = *(const float4*)(eb + (long)s * H_);
        acc.x += w * ev.x; acc.y += w * ev.y; acc.z += w * ev.z; acc.w += w * ev.w;
    }
    *(float4*)(ctx_out + (long)b * 2048 + tid * 4) = acc;
}

// ---------------------------------------------------------------------------
extern "C" void kernel_launch(void* const* d_in, const int* in_sizes, int n_in,
                              void* d_out, int out_size, void* d_ws, size_t ws_size,
                              hipStream_t stream)
{
    (void)in_sizes; (void)n_in; (void)out_size; (void)ws_size;
    const int*   src_ids  = (const int*)  d_in[0];
    const int*   tgt_ids  = (const int*)  d_in[2];
    const float* enc_emb  = (const float*)d_in[3];
    const float* dec_emb  = (const float*)d_in[4];
    const float* enc_wih0 = (const float*)d_in[5];
    const float* enc_whh0 = (const float*)d_in[6];
    const float* enc_bih0 = (const float*)d_in[7];
    const float* enc_bhh0 = (const float*)d_in[8];
    const float* enc_wih1 = (const float*)d_in[9];
    const float* enc_whh1 = (const float*)d_in[10];
    const float* enc_bih1 = (const float*)d_in[11];
    const float* enc_bhh1 = (const float*)d_in[12];
    const float* dec_wih0 = (const float*)d_in[13];
    const float* dec_whh0 = (const float*)d_in[14];
    const float* dec_bih0 = (const float*)d_in[15];
    const float* dec_bhh0 = (const float*)d_in[16];
    const float* dec_wih1 = (const float*)d_in[17];
    const float* dec_whh1 = (const float*)d_in[18];
    const float* dec_bih1 = (const float*)d_in[19];
    const float* dec_bhh1 = (const float*)d_in[20];
    const float* attn_w   = (const float*)d_in[21];
    const float* out_w    = (const float*)d_in[22];
    const float* out_b    = (const float*)d_in[23];
    float* out = (float*)d_out;

    // workspace layout (floats)
    float* ws      = (float*)d_ws;
    float* gi_enc0 = ws;                         // 2048*3072
    float* gi_dec  = gi_enc0 + 2048L * G3;       // 1536*3072
    float* enc_out = gi_dec  + 1536L * G3;       // 2048*1024  [b][t][h]
    float* proj    = enc_out + 2048L * H_;       // 2048*1024  [b][s][h]
    float* cat     = proj    + 2048L * H_;       // 1536*2048  row m=t*32+b: [d1 | ctx]
    float* states  = cat     + 1536L * 2048;     // 4*32*1024
    float* h0[2] = { states,             states + 1L*B_*H_ };
    float* h1[2] = { states + 2L*B_*H_,  states + 3L*B_*H_ };

    hipMemsetAsync(states, 0, 4L * B_ * H_ * sizeof(float), stream);

    // batched input-to-hidden GEMMs (embedding gather fused)
    gemm_bt<<<dim3(24, 16), 256, 0, stream>>>(enc_emb, E_, src_ids, 1, enc_wih0, E_, enc_bih0,
                                              gi_enc0, 0, G3, 2048, E_);
    gemm_bt<<<dim3(24, 12), 256, 0, stream>>>(dec_emb, E_, tgt_ids, 2, dec_wih0, E_ + H_, dec_bih0,
                                              gi_dec, 0, G3, 1536, E_);

    // ---- encoder ----
    int p = 0;
    for (int t = 0; t < S_; ++t) {
        gru_layer<0, 1><<<512, 256, 0, stream>>>(
            nullptr, 0, nullptr, 0, 0, nullptr,
            gi_enc0 + (long)t * B_ * G3, h0[p], enc_whh0, enc_bhh0,
            h0[1 - p], nullptr, 0);
        gru_layer<1, 0><<<512, 256, 0, stream>>>(
            h0[1 - p], H_, enc_wih1, H_, 0, enc_bih1, nullptr,
            h1[p], enc_whh1, enc_bhh1,
            h1[1 - p], enc_out + (long)t * H_, (long)S_ * H_);
        p ^= 1;
    }
    // p == 0 again after 64 steps; enc final states in h0[0], h1[0]

    // proj = enc_out @ attn_w.T   (M=2048, N=1024, K=1024)
    gemm_bt<<<dim3(8, 16), 256, 0, stream>>>(enc_out, H_, nullptr, 0, attn_w, H_, nullptr,
                                             proj, 0, H_, 2048, H_);

    // ---- decoder ----
    for (int t = 0; t < T_ - 1; ++t) {
        attention_kernel<<<B_, 256, 0, stream>>>(proj, enc_out, src_ids, h1[p],
                                                 cat + (long)t * B_ * 2048 + H_);
        gru_layer<1, 1><<<512, 256, 0, stream>>>(
            cat + (long)t * B_ * 2048 + H_, 2048,       // x = ctx
            dec_wih0, E_ + H_, E_,                      // ctx columns of wih0
            nullptr, gi_dec + (long)t * B_ * G3,
            h0[p], dec_whh0, dec_bhh0,
            h0[1 - p], nullptr, 0);
        gru_layer<1, 0><<<512, 256, 0, stream>>>(
            h0[1 - p], H_, dec_wih1, H_, 0, dec_bih1, nullptr,
            h1[p], dec_whh1, dec_bhh1,
            h1[1 - p], cat + (long)t * B_ * 2048, 2048);
        p ^= 1;
    }

    // ---- output projection: out = cat @ out_w.T + out_b ----
    gemm_bt<<<dim3(V_ / 128, 12), 256, 0, stream>>>(cat, 2048, nullptr, 0, out_w, 2048, out_b,
                                                    out, 1, 0, 1504, 2048);
}

// Round 2
// 9151.515 us; speedup vs baseline: 1.3222x; 1.3222x over previous
//
#include <hip/hip_runtime.h>
#include <math.h>

#define B_  32
#define S_  64
#define T_  48
#define V_  32000
#define E_  512
#define H_  1024
#define G3  3072   // 3*H

typedef __attribute__((ext_vector_type(8))) short short8;   // 8 bf16 (4 VGPRs)
typedef __attribute__((ext_vector_type(4))) float f32x4;    // MFMA 16x16 accumulator

__device__ __forceinline__ ushort f2bf(float x) {           // RNE f32 -> bf16
    unsigned u = __float_as_uint(x);
    return (ushort)((u + 0x7FFF + ((u >> 16) & 1)) >> 16);
}
__device__ __forceinline__ void cvt4(float4 v, ushort4& h, ushort4& l) {
    ushort h0 = f2bf(v.x), h1 = f2bf(v.y), h2 = f2bf(v.z), h3 = f2bf(v.w);
    l.x = f2bf(v.x - __uint_as_float((unsigned)h0 << 16));
    l.y = f2bf(v.y - __uint_as_float((unsigned)h1 << 16));
    l.z = f2bf(v.z - __uint_as_float((unsigned)h2 << 16));
    l.w = f2bf(v.w - __uint_as_float((unsigned)h3 << 16));
    h.x = h0; h.y = h1; h.z = h2; h.w = h3;
}

// ---------------------------------------------------------------------------
// bf16 split-3 MFMA GEMM:  C[m][n] = sum_k A[m][k]*W[n][k] (+bias[n]), fp32 io.
// A,W split hi/lo bf16 during LDS staging; C ~= Ah*Bh + Al*Bh + Ah*Bl
// (drops Al*Bl ~ 2^-16 relative -- fp32-class accuracy).
// 128x128 tile, 256 thr = 4 waves (2x2), per-wave 64x64 via 4x4 mfma 16x16x32.
// A rows optionally gathered through ids (embedding lookup).
// out_mode 0: C[m*ldc+n] (M mult of 128); out_mode 1: m=t*32+b ->
//   C[b*(47*V)+t*V+n], rows m>=M skipped.
// Grid: (N/128, ceil(M/128)). K multiple of 32, N multiple of 128.
// ---------------------------------------------------------------------------
__global__ __launch_bounds__(256)
void gemm_mfma(const float* __restrict__ A, int lda,
               const int* __restrict__ ids, int id_mode,  // 0 none, 1 enc b*64+t, 2 dec b*48+t
               const float* __restrict__ W, int ldw,
               const float* __restrict__ bias,
               float* __restrict__ C, int out_mode, int ldc,
               int M, int K)
{
    // [row][k] bf16 tiles, row stride 40 ushorts (80 B) to spread banks
    __shared__ __align__(16) ushort AhS[128][40];
    __shared__ __align__(16) ushort AlS[128][40];
    __shared__ __align__(16) ushort BhS[128][40];
    __shared__ __align__(16) ushort BlS[128][40];

    const int tid = threadIdx.x;
    const int n0  = blockIdx.x * 128;
    const int m0  = blockIdx.y * 128;
    const int sr  = tid >> 1;           // staging row 0..127
    const int sk  = (tid & 1) * 16;     // staging k base 0/16

    long abase;
    {
        int m = m0 + sr;
        if (id_mode == 0) {
            abase = (long)m * lda;
        } else {
            int t = m >> 5, b = m & 31;
            int idx = (id_mode == 1) ? (b * S_ + t) : (b * T_ + t);
            abase = (long)ids[idx] * lda;
        }
    }
    const float* Ar = A + abase + sk;
    const float* Wr = W + (long)(n0 + sr) * ldw + sk;

    const int lane = tid & 63;
    const int wv   = tid >> 6;          // wave 0..3
    const int wr   = (wv >> 1) * 64;    // wave row origin in tile
    const int wc   = (wv & 1) * 64;     // wave col origin in tile
    const int lr   = lane & 15;
    const int lk   = (lane >> 4) * 8;   // k offset of fragment

    f32x4 acc[4][4];
    const f32x4 fz = {0.f, 0.f, 0.f, 0.f};
#pragma unroll
    for (int i = 0; i < 4; ++i)
#pragma unroll
        for (int j = 0; j < 4; ++j) acc[i][j] = fz;

    for (int k0 = 0; k0 < K; k0 += 32) {
        float4 a4[4], w4[4];
#pragma unroll
        for (int q = 0; q < 4; ++q) {
            a4[q] = *(const float4*)(Ar + k0 + q * 4);
            w4[q] = *(const float4*)(Wr + k0 + q * 4);
        }
        __syncthreads();   // previous iteration's fragment reads done
#pragma unroll
        for (int q = 0; q < 4; ++q) {
            ushort4 h, l;
            cvt4(a4[q], h, l);
            *(ushort4*)&AhS[sr][sk + q * 4] = h;
            *(ushort4*)&AlS[sr][sk + q * 4] = l;
            cvt4(w4[q], h, l);
            *(ushort4*)&BhS[sr][sk + q * 4] = h;
            *(ushort4*)&BlS[sr][sk + q * 4] = l;
        }
        __syncthreads();

        short8 fah[4], fbh[4];
#pragma unroll
        for (int i = 0; i < 4; ++i) {
            fah[i] = *(const short8*)&AhS[wr + i * 16 + lr][lk];
            fbh[i] = *(const short8*)&BhS[wc + i * 16 + lr][lk];
        }
#pragma unroll
        for (int i = 0; i < 4; ++i)
#pragma unroll
            for (int j = 0; j < 4; ++j)
                acc[i][j] = __builtin_amdgcn_mfma_f32_16x16x32_bf16(fah[i], fbh[j], acc[i][j], 0, 0, 0);
        {
            short8 fal[4];
#pragma unroll
            for (int i = 0; i < 4; ++i)
                fal[i] = *(const short8*)&AlS[wr + i * 16 + lr][lk];
#pragma unroll
            for (int i = 0; i < 4; ++i)
#pragma unroll
                for (int j = 0; j < 4; ++j)
                    acc[i][j] = __builtin_amdgcn_mfma_f32_16x16x32_bf16(fal[i], fbh[j], acc[i][j], 0, 0, 0);
        }
        {
            short8 fbl[4];
#pragma unroll
            for (int j = 0; j < 4; ++j)
                fbl[j] = *(const short8*)&BlS[wc + j * 16 + lr][lk];
#pragma unroll
            for (int i = 0; i < 4; ++i)
#pragma unroll
                for (int j = 0; j < 4; ++j)
                    acc[i][j] = __builtin_amdgcn_mfma_f32_16x16x32_bf16(fah[i], fbl[j], acc[i][j], 0, 0, 0);
        }
    }

    // epilogue: C/D layout col = lane&15, row = (lane>>4)*4 + r  [m89-verified]
    float bcol[4] = {0.f, 0.f, 0.f, 0.f};
    if (bias) {
#pragma unroll
        for (int j = 0; j < 4; ++j) bcol[j] = bias[n0 + wc + j * 16 + lr];
    }
    const int rbase = (lane >> 4) * 4;
#pragma unroll
    for (int i = 0; i < 4; ++i) {
#pragma unroll
        for (int r = 0; r < 4; ++r) {
            int m = m0 + wr + i * 16 + rbase + r;
            float* crow;
            if (out_mode == 0) {
                crow = C + (long)m * ldc;
            } else {
                if (m >= M) continue;
                int t = m >> 5, b2 = m & 31;
                crow = C + (long)b2 * ((T_ - 1) * V_) + (long)t * V_;
            }
#pragma unroll
            for (int j = 0; j < 4; ++j)
                crow[n0 + wc + j * 16 + lr] = acc[i][j][r] + bcol[j];
        }
    }
}

// ---------------------------------------------------------------------------
// Fused GRU step. Each block owns TWO output units (j0, j0+1): h/x vectors
// loaded once, reused across 2 units x 3 gates.
// Block: 256 thr = (b 0..31) x (ks 0..7, K-slice of 128). Grid: 512.
// ---------------------------------------------------------------------------
template<int HAS_X, int HAS_GI>
__global__ __launch_bounds__(256)
void gru_layer(const float* __restrict__ x, int xld,
               const float* __restrict__ wx, int wxld, int wxoff,
               const float* __restrict__ bih,
               const float* __restrict__ gi_pre,   // row stride G3, rows = b (bias included)
               const float* __restrict__ h,
               const float* __restrict__ whh,
               const float* __restrict__ bhh,
               float* __restrict__ h_new,
               float* __restrict__ seq_out, long seq_stride)
{
    const int j0  = blockIdx.x * 2;
    const int tid = threadIdx.x;
    const int b   = tid & 31;
    const int ks  = tid >> 5;
    __shared__ float redh[2][3][8][32];
    __shared__ float redx[2][3][8][32];

    const float* hr  = h + (long)b * H_;
    const float* wh  = whh + (long)j0 * H_;
    const float* xr  = nullptr;
    const float* wxb = nullptr;
    if (HAS_X) {
        xr  = x + (long)b * xld;
        wxb = wx + (long)j0 * wxld + wxoff;
    }

    float ah[2][3] = {};
    float ax[2][3] = {};
    const int k0 = ks * 128;
#pragma unroll 2
    for (int k = k0; k < k0 + 128; k += 4) {
        float4 hv = *(const float4*)(hr + k);
        float4 xv;
        if (HAS_X) xv = *(const float4*)(xr + k);
#pragma unroll
        for (int u = 0; u < 2; ++u) {
#pragma unroll
            for (int g = 0; g < 3; ++g) {
                float4 wv = *(const float4*)(wh + ((long)g * H_ + u) * H_ + k);
                ah[u][g] += hv.x*wv.x + hv.y*wv.y + hv.z*wv.z + hv.w*wv.w;
                if (HAS_X) {
                    float4 uv = *(const float4*)(wxb + ((long)g * H_ + u) * wxld + k);
                    ax[u][g] += xv.x*uv.x + xv.y*uv.y + xv.z*uv.z + xv.w*uv.w;
                }
            }
        }
    }
#pragma unroll
    for (int u = 0; u < 2; ++u)
#pragma unroll
        for (int g = 0; g < 3; ++g) {
            redh[u][g][ks][b] = ah[u][g];
            if (HAS_X) redx[u][g][ks][b] = ax[u][g];
        }
    __syncthreads();
    if (tid < 64) {
        const int u  = tid >> 5;
        const int bb = tid & 31;
        const int j  = j0 + u;
        float gh0 = bhh[j], gh1 = bhh[H_ + j], gh2 = bhh[2*H_ + j];
#pragma unroll
        for (int q = 0; q < 8; ++q) {
            gh0 += redh[u][0][q][bb]; gh1 += redh[u][1][q][bb]; gh2 += redh[u][2][q][bb];
        }
        float gi0, gi1, gi2;
        if (HAS_GI) {
            const float* g = gi_pre + (long)bb * G3;
            gi0 = g[j]; gi1 = g[H_ + j]; gi2 = g[2*H_ + j];
        } else {
            gi0 = bih[j]; gi1 = bih[H_ + j]; gi2 = bih[2*H_ + j];
        }
        if (HAS_X) {
#pragma unroll
            for (int q = 0; q < 8; ++q) {
                gi0 += redx[u][0][q][bb]; gi1 += redx[u][1][q][bb]; gi2 += redx[u][2][q][bb];
            }
        }
        float r = 1.f / (1.f + expf(-(gi0 + gh0)));
        float z = 1.f / (1.f + expf(-(gi1 + gh1)));
        float n = tanhf(gi2 + r * gh2);
        float hv = h[(long)bb * H_ + j];
        float o = (1.f - z) * n + z * hv;
        h_new[(long)bb * H_ + j] = o;
        if (seq_out) seq_out[(long)bb * seq_stride + j] = o;
    }
}

// ---------------------------------------------------------------------------
// Attention for one decoder step. Grid: 32 (b). Block: 256.
// ---------------------------------------------------------------------------
__global__ __launch_bounds__(256)
void attention_kernel(const float* __restrict__ proj,
                      const float* __restrict__ enc_out,
                      const int* __restrict__ src_ids,
                      const float* __restrict__ d1,
                      float* __restrict__ ctx_out)
{
    const int b = blockIdx.x;
    const int tid = threadIdx.x;
    __shared__ __align__(16) float dl[H_];
    __shared__ float attn[S_];

    *(float4*)&dl[tid * 4] = *(const float4*)(d1 + (long)b * H_ + tid * 4);
    __syncthreads();

    const int lane = tid & 63, wid = tid >> 6;
    for (int s = wid; s < S_; s += 4) {
        const float* pr = proj + ((long)b * S_ + s) * H_;
        float a = 0.f;
#pragma unroll
        for (int c = 0; c < 4; ++c) {
            float4 pv = *(const float4*)(pr + c * 256 + lane * 4);
            float4 dv = *(const float4*)&dl[c * 256 + lane * 4];
            a += pv.x*dv.x + pv.y*dv.y + pv.z*dv.z + pv.w*dv.w;
        }
#pragma unroll
        for (int off = 32; off > 0; off >>= 1) a += __shfl_xor(a, off);
        if (lane == 0) attn[s] = (src_ids[b * S_ + s] != 0) ? a : -1e9f;
    }
    __syncthreads();
    if (tid < 64) {
        float v = attn[tid];
        float mx = v;
#pragma unroll
        for (int off = 32; off > 0; off >>= 1) mx = fmaxf(mx, __shfl_xor(mx, off));
        float e = expf(v - mx);
        float sm = e;
#pragma unroll
        for (int off = 32; off > 0; off >>= 1) sm += __shfl_xor(sm, off);
        attn[tid] = e / sm;
    }
    __syncthreads();
    float4 acc = make_float4(0.f, 0.f, 0.f, 0.f);
    const float* eb = enc_out + (long)b * S_ * H_ + tid * 4;
    for (int s = 0; s < S_; ++s) {
        float w = attn[s];
        float4 ev = *(const float4*)(eb + (long)s * H_);
        acc.x += w * ev.x; acc.y += w * ev.y; acc.z += w * ev.z; acc.w += w * ev.w;
    }
    *(float4*)(ctx_out + (long)b * 2048 + tid * 4) = acc;
}

// ---------------------------------------------------------------------------
extern "C" void kernel_launch(void* const* d_in, const int* in_sizes, int n_in,
                              void* d_out, int out_size, void* d_ws, size_t ws_size,
                              hipStream_t stream)
{
    (void)in_sizes; (void)n_in; (void)out_size; (void)ws_size;
    const int*   src_ids  = (const int*)  d_in[0];
    const int*   tgt_ids  = (const int*)  d_in[2];
    const float* enc_emb  = (const float*)d_in[3];
    const float* dec_emb  = (const float*)d_in[4];
    const float* enc_wih0 = (const float*)d_in[5];
    const float* enc_whh0 = (const float*)d_in[6];
    const float* enc_bih0 = (const float*)d_in[7];
    const float* enc_bhh0 = (const float*)d_in[8];
    const float* enc_wih1 = (const float*)d_in[9];
    const float* enc_whh1 = (const float*)d_in[10];
    const float* enc_bih1 = (const float*)d_in[11];
    const float* enc_bhh1 = (const float*)d_in[12];
    const float* dec_wih0 = (const float*)d_in[13];
    const float* dec_whh0 = (const float*)d_in[14];
    const float* dec_bih0 = (const float*)d_in[15];
    const float* dec_bhh0 = (const float*)d_in[16];
    const float* dec_wih1 = (const float*)d_in[17];
    const float* dec_whh1 = (const float*)d_in[18];
    const float* dec_bih1 = (const float*)d_in[19];
    const float* dec_bhh1 = (const float*)d_in[20];
    const float* attn_w   = (const float*)d_in[21];
    const float* out_w    = (const float*)d_in[22];
    const float* out_b    = (const float*)d_in[23];
    float* out = (float*)d_out;

    // workspace layout (floats) -- same footprint as previous round
    float* ws      = (float*)d_ws;
    float* gi_enc0 = ws;                         // 2048*3072 (reused as gi_enc1)
    float* gi_dec  = gi_enc0 + 2048L * G3;       // 1536*3072
    float* enc_out = gi_dec  + 1536L * G3;       // 2048*1024  [b][t][h]
    float* proj    = enc_out + 2048L * H_;       // 2048*1024  [b][s][h]
    float* cat     = proj    + 2048L * H_;       // 1536*2048  row m=t*32+b: [d1 | ctx]
    float* states  = cat     + 1536L * 2048;     // 4*32*1024
    float* h0[2] = { states,             states + 1L*B_*H_ };
    float* h1[2] = { states + 2L*B_*H_,  states + 3L*B_*H_ };
    float* enc_l0  = cat;                        // alias: layer-0 seq [t][b][h], free pre-decoder

    hipMemsetAsync(states, 0, 4L * B_ * H_ * sizeof(float), stream);

    // batched input-to-hidden GEMMs (embedding gather fused)
    gemm_mfma<<<dim3(24, 16), 256, 0, stream>>>(enc_emb, E_, src_ids, 1, enc_wih0, E_, enc_bih0,
                                                gi_enc0, 0, G3, 2048, E_);
    gemm_mfma<<<dim3(24, 12), 256, 0, stream>>>(dec_emb, E_, tgt_ids, 2, dec_wih0, E_ + H_, dec_bih0,
                                                gi_dec, 0, G3, 1536, E_);

    // ---- encoder layer 0 (recurrent only; x-side precomputed in gi_enc0) ----
    int p = 0;
    for (int t = 0; t < S_; ++t) {
        gru_layer<0, 1><<<512, 256, 0, stream>>>(
            nullptr, 0, nullptr, 0, 0, nullptr,
            gi_enc0 + (long)t * B_ * G3, h0[p], enc_whh0, enc_bhh0,
            h0[1 - p], enc_l0 + (long)t * B_ * H_, (long)H_);
        p ^= 1;
    }
    // p == 0 again; h0 final in h0[0]

    // batched layer-1 input GEMM: gi_enc1 = enc_l0 @ wih1.T  (overwrites gi_enc0)
    gemm_mfma<<<dim3(24, 16), 256, 0, stream>>>(enc_l0, H_, nullptr, 0, enc_wih1, H_, enc_bih1,
                                                gi_enc0, 0, G3, 2048, H_);

    // ---- encoder layer 1 (recurrent only) ----
    p = 0;
    for (int t = 0; t < S_; ++t) {
        gru_layer<0, 1><<<512, 256, 0, stream>>>(
            nullptr, 0, nullptr, 0, 0, nullptr,
            gi_enc0 + (long)t * B_ * G3, h1[p], enc_whh1, enc_bhh1,
            h1[1 - p], enc_out + (long)t * H_, (long)S_ * H_);
        p ^= 1;
    }
    // p == 0; enc final states in h0[0], h1[0]

    // proj = enc_out @ attn_w.T   (M=2048, N=1024, K=1024)
    gemm_mfma<<<dim3(8, 16), 256, 0, stream>>>(enc_out, H_, nullptr, 0, attn_w, H_, nullptr,
                                               proj, 0, H_, 2048, H_);

    // ---- decoder ----
    for (int t = 0; t < T_ - 1; ++t) {
        attention_kernel<<<B_, 256, 0, stream>>>(proj, enc_out, src_ids, h1[p],
                                                 cat + (long)t * B_ * 2048 + H_);
        gru_layer<1, 1><<<512, 256, 0, stream>>>(
            cat + (long)t * B_ * 2048 + H_, 2048,       // x = ctx
            dec_wih0, E_ + H_, E_,                      // ctx columns of wih0
            nullptr, gi_dec + (long)t * B_ * G3,
            h0[p], dec_whh0, dec_bhh0,
            h0[1 - p], nullptr, 0);
        gru_layer<1, 0><<<512, 256, 0, stream>>>(
            h0[1 - p], H_, dec_wih1, H_, 0, dec_bih1, nullptr,
            h1[p], dec_whh1, dec_bhh1,
            h1[1 - p], cat + (long)t * B_ * 2048, 2048);
        p ^= 1;
    }

    // ---- output projection: out = cat @ out_w.T + out_b ----
    gemm_mfma<<<dim3(V_ / 128, 12), 256, 0, stream>>>(cat, 2048, nullptr, 0, out_w, 2048, out_b,
                                                      out, 1, 0, 1504, 2048);
}